// Round 6
// baseline (358.749 us; speedup 1.0000x reference)
//
#include <hip/hip_runtime.h>
#include <hip/hip_bf16.h>

#define TOKENS 16384
#define HIDDEN 4096
#define EXPERTS 64

typedef __attribute__((ext_vector_type(8))) short short8;
typedef __attribute__((ext_vector_type(4))) float f32x4;
typedef __attribute__((ext_vector_type(4))) unsigned int u32x4;

// Dequantized weights in MFMA B-fragment order (uint4 granularity):
//   uint4 index = kk*256 + nt*64 + lane   (kk = K-chunk of 32, nt = expert group)
//   lane's 8 ushorts j=0..7: expert e = nt*16+(lane&15), k = kk*32+(lane>>4)*8+j
// 128 kk * 4 nt * 64 lanes = 32768 uint4 = 512 KB (L2/L3-resident)
__device__ __align__(16) ushort g_B[128 * 4 * 64 * 8];

union Frag {
    u32x4 u;
    short8 s;
};

__device__ __forceinline__ ushort f2bf_rtne(float f) {
    union { float f; unsigned u; } c; c.f = f;
    unsigned u = c.u;
    return (ushort)((u + 0x7FFF + ((u >> 16) & 1)) >> 16);
}

__device__ __forceinline__ unsigned pk_bf16(float lo, float hi) {
    __hip_bfloat162 h = __float22bfloat162_rn(make_float2(lo, hi));
    unsigned r;
    __builtin_memcpy(&r, &h, 4);
    return r;
}

__device__ __forceinline__ void loadA(const float* p, f32x4& a0, f32x4& a1) {
    a0 = __builtin_nontemporal_load(reinterpret_cast<const f32x4*>(p));
    a1 = __builtin_nontemporal_load(reinterpret_cast<const f32x4*>(p) + 1);
}

// One thread per g_B element (262144 threads); also zeroes d_out (4 floats each)
// for the split-K atomic accumulation in the main kernel.
__global__ __launch_bounds__(256) void prep_kernel(const int* __restrict__ w,
                                                   const float* __restrict__ sc,
                                                   float* __restrict__ out) {
    int tid = blockIdx.x * 256 + threadIdx.x;   // 0..262143
    reinterpret_cast<float4*>(out)[tid] = make_float4(0.f, 0.f, 0.f, 0.f);

    int j    = tid & 7;
    int lane = (tid >> 3) & 63;
    int nt   = (tid >> 9) & 3;
    int kk   = tid >> 11;
    int e = nt * 16 + (lane & 15);
    int k = kk * 32 + (lane >> 4) * 8 + j;
    float v = (float)w[e * HIDDEN + k] * sc[e];
    g_B[tid] = f2bf_rtne(v);
}

// Grid: (64 row-superblocks, 8 K-slices) = 512 blocks = exactly 2/CU, ONE
// residency round (no inter-round drain, single tail, B staged once per block).
// Block: 512 threads = 8 waves x 16 rows; processes 2 row-tiles of 128 rows
// with the same 64 KB LDS B-slice. K-loop VMEM is only the A stream
// (2 nontemporal dwordx4/iter, depth-2 register prefetch, #pragma unroll 2
// pins the pipeline shape — prevents full-unroll VGPR blowup/spill).
__global__ __launch_bounds__(512, 4) void moe_router_kernel(const float* __restrict__ x,
                                                            float* __restrict__ out) {
    __shared__ u32x4 smB[4096];   // exactly 64 KB

    const int mb0  = blockIdx.x * 2;      // row-tile pair: 0,2,4,..,126
    const int kq   = blockIdx.y;          // 0..7
    const int tid  = threadIdx.x;
    const int wave = tid >> 6;            // 0..7
    const int lane = tid & 63;

    // ---- stage B slice: 4096 uint4, 8 per thread, linear copy ----
    const u32x4* gB = reinterpret_cast<const u32x4*>(g_B) + (size_t)kq * 4096;
#pragma unroll
    for (int i = 0; i < 8; ++i) smB[tid + i * 512] = gB[tid + i * 512];
    __syncthreads();

    const int kb = kq * 512 + (lane >> 4) * 8;

    for (int t = 0; t < 2; ++t) {
        const int row0 = (mb0 + t) * 128 + wave * 16;
        const int m    = row0 + (lane & 15);
        const float* xs = x + (size_t)m * HIDDEN + kb;

        f32x4 acc0 = {0.f, 0.f, 0.f, 0.f};
        f32x4 acc1 = {0.f, 0.f, 0.f, 0.f};
        f32x4 acc2 = {0.f, 0.f, 0.f, 0.f};
        f32x4 acc3 = {0.f, 0.f, 0.f, 0.f};

        // ---- prologue: A for s=0,1 in flight; B frags for s=0 ----
        f32x4 a0c, a1c, a0n, a1n;
        loadA(xs, a0c, a1c);
        loadA(xs + 32, a0n, a1n);
        u32x4 b0c = smB[lane];
        u32x4 b1c = smB[lane + 64];
        u32x4 b2c = smB[lane + 128];
        u32x4 b3c = smB[lane + 192];

#pragma unroll 2
        for (int s = 0; s < 16; ++s) {
            // prefetch A(s+2): keeps 2 iters (4 KB/wave) of HBM loads in flight
            f32x4 a0f = a0n, a1f = a1n;
            if (s < 14) loadA(xs + (s + 2) * 32, a0f, a1f);

            // prefetch B(s+1) frags from LDS
            u32x4 b0n = b0c, b1n = b1c, b2n = b2c, b3n = b3c;
            if (s < 15) {
                const u32x4* bp = smB + (s + 1) * 256 + lane;
                b0n = bp[0];
                b1n = bp[64];
                b2n = bp[128];
                b3n = bp[192];
            }

            // pack current A into bf16 fragment
            Frag af;
            af.u.x = pk_bf16(a0c.x, a0c.y);
            af.u.y = pk_bf16(a0c.z, a0c.w);
            af.u.z = pk_bf16(a1c.x, a1c.y);
            af.u.w = pk_bf16(a1c.z, a1c.w);

            Frag b0, b1, b2, b3;
            b0.u = b0c; b1.u = b1c; b2.u = b2c; b3.u = b3c;
            acc0 = __builtin_amdgcn_mfma_f32_16x16x32_bf16(af.s, b0.s, acc0, 0, 0, 0);
            acc1 = __builtin_amdgcn_mfma_f32_16x16x32_bf16(af.s, b1.s, acc1, 0, 0, 0);
            acc2 = __builtin_amdgcn_mfma_f32_16x16x32_bf16(af.s, b2.s, acc2, 0, 0, 0);
            acc3 = __builtin_amdgcn_mfma_f32_16x16x32_bf16(af.s, b3.s, acc3, 0, 0, 0);

            // rotate pipeline registers
            a0c = a0n; a1c = a1n; a0n = a0f; a1n = a1f;
            b0c = b0n; b1c = b1n; b2c = b2n; b3c = b3n;
        }

        // Epilogue: C/D layout col = lane&15, row = (lane>>4)*4 + r  [m89/m91]
        const int trow = row0 + (lane >> 4) * 4;
        const int col  = lane & 15;
        float* op = out + (size_t)trow * EXPERTS + col;
#pragma unroll
        for (int r = 0; r < 4; ++r) {
            atomicAdd(op + (size_t)r * EXPERTS + 0,  acc0[r]);
            atomicAdd(op + (size_t)r * EXPERTS + 16, acc1[r]);
            atomicAdd(op + (size_t)r * EXPERTS + 32, acc2[r]);
            atomicAdd(op + (size_t)r * EXPERTS + 48, acc3[r]);
        }
    }
}

extern "C" void kernel_launch(void* const* d_in, const int* in_sizes, int n_in,
                              void* d_out, int out_size, void* d_ws, size_t ws_size,
                              hipStream_t stream) {
    const float* x  = (const float*)d_in[0];
    const int*   w  = (const int*)d_in[1];
    const float* sc = (const float*)d_in[2];
    float* out = (float*)d_out;

    // prep: dequant weights into MFMA fragment layout + zero output accumulator
    prep_kernel<<<1024, 256, 0, stream>>>(w, sc, out);

    // main: B-in-LDS, pure A-stream VMEM, split-K=8, 2 row-tiles per block,
    // single residency round (512 blocks = 2/CU)
    dim3 grid(TOKENS / 256, 8);
    moe_router_kernel<<<grid, 512, 0, stream>>>(x, out);
}